// Round 4
// baseline (876.410 us; speedup 1.0000x reference)
//
#include <hip/hip_runtime.h>
#include <math.h>

#define NVIEW 720
#define NDCT  1024
#define NZ    32
#define NX    512
#define NY    512

#define NR  24       // staged detector rows: tile i-spread <= 22, +1 for i+1 row
#define RS16 12      // dwords per staged row (8 data dw = 16 z f16, + 4 pad = 48 B).
                     // b128 window start of row r = (12r) mod 32 = {0,12,24,4,16,28,8,20}
                     // over r mod 8 -> perfectly tiled 4-bank windows, only r vs r+8
                     // alias (2-way, measured-free class).

typedef unsigned int uint;

// ---- guaranteed-single-instruction f16xf32 FMA (no fdot2: R1-R3 counters fit
// fdot2 being legalized to ~4 VALU ops; v_fma_mix_f32 is 1 op, f32 accumulate).
#define MIXLO(ACC, U, WF) \
    asm("v_fma_mix_f32 %0, %1, %2, %0 op_sel:[0,0,0] op_sel_hi:[1,0,0]" \
        : "+v"(ACC) : "v"(U), "v"(WF))
#define MIXHI(ACC, U, WF) \
    asm("v_fma_mix_f32 %0, %1, %2, %0 op_sel:[1,0,0] op_sel_hi:[1,0,0]" \
        : "+v"(ACC) : "v"(U), "v"(WF))

// One dw holds f16 for (z=2j, z=2j+1) of one row. Sample pair from rows A (g0)
// and B (g1) with weights VV=1-w, WW=w:  acc_z += VV*A_z + WW*B_z.
#define MIXPAIR(A0, A1, UA, UB, VV, WW) do { \
    MIXLO(A0, UA, VV); MIXLO(A0, UB, WW); \
    MIXHI(A1, UA, VV); MIXHI(A1, UB, WW); \
} while (0)

// Sample one pixel's 16 z from row regs (RA0,RA1)=row i, (RB0,RB1)=row i+1.
#define PXSAMPLE(ACC, RA0, RA1, RB0, RB1, VV, WW) do { \
    MIXPAIR(ACC[ 0], ACC[ 1], RA0.x, RB0.x, VV, WW); \
    MIXPAIR(ACC[ 2], ACC[ 3], RA0.y, RB0.y, VV, WW); \
    MIXPAIR(ACC[ 4], ACC[ 5], RA0.z, RB0.z, VV, WW); \
    MIXPAIR(ACC[ 6], ACC[ 7], RA0.w, RB0.w, VV, WW); \
    MIXPAIR(ACC[ 8], ACC[ 9], RA1.x, RB1.x, VV, WW); \
    MIXPAIR(ACC[10], ACC[11], RA1.y, RB1.y, VV, WW); \
    MIXPAIR(ACC[12], ACC[13], RA1.z, RB1.z, VV, WW); \
    MIXPAIR(ACC[14], ACC[15], RA1.w, RB1.w, VV, WW); \
} while (0)

__device__ __forceinline__ uint packh2(float a, float b) {
    union { _Float16 h[2]; uint u; } r;
    r.h[0] = (_Float16)a;            // RNE
    r.h[1] = (_Float16)b;
    return r.u;
}

// packed16[v][i][zpair]: per (v,i) 16 dw = 32 f16, z-contiguous.
// Input x: (Z=32, 1, NVIEW, NDCT). No neighbor/delta needed anymore (g1 comes
// from row i+1 at consume time), so no shuffle chain.
__global__ __launch_bounds__(64) void pack16_kernel(const float* __restrict__ x,
                                                    uint* __restrict__ packed) {
    __shared__ uint tr[64 * 17];             // [i_local][zpair], stride 17 -> ~free
    const int l  = threadIdx.x;              // 0..63
    const int v  = blockIdx.x;               // 0..719
    const int ib = blockIdx.y * 64;          // i block base
    const float* rowbase = x + (size_t)v * NDCT + ib;

    for (int zp = 0; zp < 16; ++zp) {
        float a0 = rowbase[(size_t)(2 * zp)     * (NVIEW * NDCT) + l];  // coalesced
        float a1 = rowbase[(size_t)(2 * zp + 1) * (NVIEW * NDCT) + l];
        tr[l * 17 + zp] = packh2(a0, a1);
    }
    __syncthreads();

    uint* obase = packed + ((size_t)v * NDCT + ib) * 16;
    #pragma unroll
    for (int it = 0; it < 4; ++it) {
        int c  = it * 64 + l;                // uint4 chunk 0..255; dst dw = 4c
        int il = c >> 2;                     // i_local
        int zp = (c & 3) * 4;
        uint4 w4;
        w4.x = tr[il * 17 + zp + 0];
        w4.y = tr[il * 17 + zp + 1];
        w4.z = tr[il * 17 + zp + 2];
        w4.w = tr[il * 17 + zp + 3];
        *(uint4*)(obase + (size_t)c * 4) = w4;
    }
}

// 16x16 pixel tile, 128 threads (8x16), 2 adjacent x-pixels + 16 z per thread.
// f16-only rows: px needs rows (i, i+1); px1 shares one row with px0 whenever
// i1 == i0 (prob 1-|c|), else a single masked reload shifts the row pair by one
// (direction = wave-uniform sign of c). All sampling via v_fma_mix_f32.
__global__ __launch_bounds__(128, 4) void bp_lds16(const uint* __restrict__ packed,
                                                   float* __restrict__ out) {
    __shared__ float4 tab[NVIEW];                        // 11520 B
    __shared__ __align__(16) uint stage[2][NR * RS16];   // 2 x 1152 B

    const int tid = threadIdx.y * 8 + threadIdx.x;       // 0..127
    const int g   = blockIdx.z;                          // z-group (16 z each)
    const float xf0 = (float)(int)(blockIdx.x * 16) - 255.5f;
    const float yf0 = (float)(int)(blockIdx.y * 16) - 255.5f;

    // Per-view cos/sin + block-uniform floor(t_min) folded as bval = 511.5 - imin.
    // bval fold perturbs t by <= 1 ULP(512); trunc at 0 and NR slack absorb it.
    for (int v = tid; v < NVIEW; v += 128) {
        float th = (float)v * (float)(M_PI / NVIEW);
        float s, c;
        sincosf(th, &s, &c);
        float b0 = fmaf(yf0, s, 511.5f);
        float b1 = fmaf(yf0 + 15.0f, s, 511.5f);
        float t00 = fmaf(xf0, c, b0);
        float t10 = fmaf(xf0 + 15.0f, c, b0);
        float t01 = fmaf(xf0, c, b1);
        float t11 = fmaf(xf0 + 15.0f, c, b1);
        int imin = (int)fminf(fminf(t00, t10), fminf(t01, t11));
        tab[v] = make_float4(c, s, 511.5f - (float)imin, __int_as_float(imin));
    }
    __syncthreads();

    const int x0 = blockIdx.x * 16 + threadIdx.x * 2;    // even
    const int y  = blockIdx.y * 16 + threadIdx.y;
    const float xf = (float)x0 - 255.5f;
    const float yf = (float)y  - 255.5f;

    float acc0[16], acc1[16];
    #pragma unroll
    for (int z = 0; z < 16; ++z) { acc0[z] = 0.0f; acc1[z] = 0.0f; }

    // Staging: NR rows x 8 dw = 48 x4-chunks over 2 waves (24 lanes each).
    const int  wv   = tid >> 6;
    const int  ln   = tid & 63;
    const bool sact = (ln < 24);
    const int  slot = wv * 24 + ln;          // 0..47
    const int  sr   = slot >> 1;             // staged row 0..23
    const int  sch  = slot & 1;              // 16B chunk 0..1
    const size_t sg_off = ((size_t)sr << 4) + (g << 3) + (sch << 2);  // global dw off
    const int  swr  = sr * RS16 + (sch << 2);                         // LDS dw off

    // ---- prologue: stage view 0 into buffer 0 ----
    float4 t4 = tab[0];
    uint4 st;
    if (sact) {
        st = *(const uint4*)(packed + ((size_t)__float_as_int(t4.w) << 4) + sg_off);
        *(uint4*)&stage[0][swr] = st;
    }
    __syncthreads();

    #pragma unroll 2
    for (int v = 0; v < NVIEW; ++v) {
        // [A] next-view tab read + staging load (published at [F]; ~full view flight)
        float4 t4n = t4;
        if (v + 1 < NVIEW) t4n = tab[v + 1];
        if (sact && v + 1 < NVIEW) {
            st = *(const uint4*)(packed + ((size_t)(v + 1) << 14)
                                 + ((size_t)__float_as_int(t4n.w) << 4) + sg_off);
        }

        const float c = t4.x, s = t4.y;
        float t0 = fmaf(xf, c, fmaf(yf, s, t4.z));   // t - imin, >= -1ulp
        float t1 = t0 + c;
        int   i0 = (int)t0;                          // trunc(-eps) = 0: safe
        int   i1 = (int)t1;
        float w0 = t0 - (float)i0;
        float w1 = t1 - (float)i1;
        float v0 = 1.0f - w0;
        float v1 = 1.0f - w1;

        // [C] px0 rows: (i0, i0+1) -> (ra0,ra1),(rb0,rb1); 4x b128 off one base
        // (imm offsets 0/16/48/64 B).
        const uint* sp = stage[v & 1] + i0 * RS16;
        uint4 ra0 = *(const uint4*)(sp);
        uint4 ra1 = *(const uint4*)(sp + 4);
        uint4 rb0 = *(const uint4*)(sp + RS16);
        uint4 rb1 = *(const uint4*)(sp + RS16 + 4);

        PXSAMPLE(acc0, ra0, ra1, rb0, rb1, v0, w0);

        // [D] shift row pair for px1 where it differs (wave-uniform direction,
        // divergent mask; inactive lanes keep px0's pair which is correct).
        if (c >= 0.0f) {                     // i1 in {i0, i0+1}
            if (i1 != i0) {
                ra0 = rb0; ra1 = rb1;
                const uint* s2 = stage[v & 1] + (i1 + 1) * RS16;
                rb0 = *(const uint4*)(s2);
                rb1 = *(const uint4*)(s2 + 4);
            }
        } else {                             // i1 in {i0-1, i0}
            if (i1 != i0) {
                rb0 = ra0; rb1 = ra1;
                const uint* s2 = stage[v & 1] + i1 * RS16;
                ra0 = *(const uint4*)(s2);
                ra1 = *(const uint4*)(s2 + 4);
            }
        }

        PXSAMPLE(acc1, ra0, ra1, rb0, rb1, v1, w1);

        // [F] publish view v+1 stage (vmcnt waits only on st, issued at [A])
        if (sact && v + 1 < NVIEW) *(uint4*)&stage[(v + 1) & 1][swr] = st;
        // [G] one barrier per view: orders iter-(v+1) writes of a buffer after
        // all iter-v reads of it -> race-free double buffer
        __syncthreads();
        t4 = t4n;
    }

    const float scale = 0.0043633231299858236f;  // pi / 720
    #pragma unroll
    for (int lz = 0; lz < 16; ++lz) {
        float2 o = make_float2(acc0[lz] * scale, acc1[lz] * scale);
        *(float2*)(out + (((size_t)(g * 16 + lz)) * NY + y) * NX + x0) = o;
    }
}

// Fallback (ws too small for packed array): direct fp32, two loads per sample.
__global__ __launch_bounds__(256) void bp_direct(const float* __restrict__ xin,
                                                 float* __restrict__ out) {
    __shared__ float2 cs[NVIEW];
    int lt = threadIdx.y * 64 + threadIdx.x;
    for (int v = lt; v < NVIEW; v += 256) {
        float th = (float)v * (float)(M_PI / NVIEW);
        float s, c;
        sincosf(th, &s, &c);
        cs[v] = make_float2(c, s);
    }
    __syncthreads();

    int x = blockIdx.x * 64 + threadIdx.x;
    int y = blockIdx.y * 4 + threadIdx.y;
    float xf = (float)x - 255.5f;
    float yf = (float)y - 255.5f;

    float acc[NZ];
    #pragma unroll
    for (int z = 0; z < NZ; ++z) acc[z] = 0.0f;

    for (int v = 0; v < NVIEW; ++v) {
        float2 a = cs[v];
        float t  = fmaf(xf, a.x, fmaf(yf, a.y, 511.5f));
        int   i0 = (int)t;
        float w  = t - (float)i0;
        const float* p = xin + (size_t)v * NDCT + i0;
        #pragma unroll
        for (int z = 0; z < NZ; ++z) {
            float g0 = p[(size_t)z * NVIEW * NDCT];
            float g1 = p[(size_t)z * NVIEW * NDCT + 1];
            acc[z] += fmaf(w, g1 - g0, g0);
        }
    }

    const float scale = 0.0043633231299858236f;
    #pragma unroll
    for (int z = 0; z < NZ; ++z) {
        out[((size_t)z * NY + y) * NX + x] = acc[z] * scale;
    }
}

extern "C" void kernel_launch(void* const* d_in, const int* in_sizes, int n_in,
                              void* d_out, int out_size, void* d_ws, size_t ws_size,
                              hipStream_t stream) {
    const float* x = (const float*)d_in[0];
    float* out = (float*)d_out;

    const size_t packed_bytes = (size_t)NVIEW * NDCT * 16 * sizeof(uint);  // 47.2 MB

    if (ws_size >= packed_bytes) {
        uint* packed = (uint*)d_ws;
        pack16_kernel<<<dim3(NVIEW, NDCT / 64), 64, 0, stream>>>(x, packed);
        bp_lds16<<<dim3(NX / 16, NY / 16, 2), dim3(8, 16), 0, stream>>>(packed, out);
    } else {
        bp_direct<<<dim3(NX / 64, NY / 4), dim3(64, 4), 0, stream>>>(x, out);
    }
}

// Round 5
// 862.145 us; speedup vs baseline: 1.0165x; 1.0165x over previous
//
#include <hip/hip_runtime.h>
#include <math.h>

#define NVIEW 720
#define NDCT  1024
#define NZ    32
#define NX    512
#define NY    512

#define ZG  8        // z per block (z-split 4: doubles resident waves vs R1's ZG=16)
#define NR  24       // staged detector rows (16x16 tile: i0 spread <= 22, +1 for i+1)
#define RS  12       // dwords per staged row (8 data = 8 z packed words + 4 pad; 48 B).
                     // b128 start of row r = 12r mod 32 = {0,12,24,4,16,28,8,20}:
                     // tiled over r mod 8, only r vs r+8 alias (2-way = free class).

typedef unsigned int uint;

#if __has_builtin(__builtin_amdgcn_fdot2)
#define USE_FDOT2 1
typedef _Float16 half2v __attribute__((ext_vector_type(2)));
#else
#define USE_FDOT2 0
#endif

// Round fp32 -> bf16 bits (RNE).
__device__ __forceinline__ uint f2bf_rne(float f) {
    uint u = __float_as_uint(f);
    return (u + 0x7fffu + ((u >> 16) & 1u)) >> 16;
}

// Packed word for (v, i, z):
//  fdot2 path:  lo16 = f16(g0 = p[i]), hi16 = f16(d = p[i+1]-p[i])
//               consumer: acc = v_dot2_f32_f16(word, {1.0, w}, acc)
//  fallback:    hi16 = dithered bf16(g0), lo16 = bf16(d)
__device__ __forceinline__ uint pack_word(float a, float b) {
#if USE_FDOT2
    union { _Float16 h[2]; uint u; } r;
    r.h[0] = (_Float16)a;         // g0 in low half
    r.h[1] = (_Float16)(b - a);   // d  in high half
    return r.u;
#else
    uint lo = f2bf_rne(b - a);
    uint u  = (f2bf_rne(a) << 16) | lo;
    uint up = u + 0x10000u, um = u - 0x10000u;
    float e0 = fabsf(__uint_as_float(u)  - a);
    float e1 = fabsf(__uint_as_float(up) - a);
    float e2 = fabsf(__uint_as_float(um) - a);
    if (e1 < e0) { u = up; e0 = e1; }
    if (e2 < e0) { u = um; }
    return u;
#endif
}

// packed[v][i][z], z contiguous (32 dw per (v,i)).  (R1-proven kernel, unchanged.)
__global__ __launch_bounds__(64) void pack_kernel(const float* __restrict__ x,
                                                  uint* __restrict__ packed) {
    __shared__ uint tr[64 * 33];             // [i_local][z], stride 33 -> conflict-free
    const int l  = threadIdx.x;              // 0..63
    const int v  = blockIdx.x;               // 0..719
    const int ib = blockIdx.y * 64;          // i block base
    const bool last = (ib + 64 >= NDCT);
    const float* rowbase = x + (size_t)v * NDCT + ib;

    float pre = 0.0f;
    if (l < NZ && !last) pre = rowbase[(size_t)l * (NVIEW * NDCT) + 64];

    for (int z = 0; z < NZ; ++z) {
        const float* r = rowbase + (size_t)z * (NVIEW * NDCT);
        float a   = r[l];                    // coalesced 256B
        float a64 = __shfl(pre, z);
        float b   = __shfl(a, l + 1);
        if (l == 63) b = a64;                // neighbor across wave boundary
        tr[l * 33 + z] = pack_word(a, b);
    }
    __syncthreads();

    uint* obase = packed + ((size_t)v * NDCT + ib) * 32;
    #pragma unroll
    for (int it = 0; it < 8; ++it) {
        int c  = it * 64 + l;                // chunk 0..511; dst dword = 4c (coalesced)
        int il = c >> 3;
        int zc = (c & 7) * 4;
        uint4 w4;
        w4.x = tr[il * 33 + zc + 0];
        w4.y = tr[il * 33 + zc + 1];
        w4.z = tr[il * 33 + zc + 2];
        w4.w = tr[il * 33 + zc + 3];
        *(uint4*)(obase + (size_t)c * 4) = w4;
    }
}

#if USE_FDOT2
#define SAMP(A, zz, uu, WP, WF) do { \
    union { uint q; half2v h; } _c; _c.q = (uu); \
    A[zz] = __builtin_amdgcn_fdot2(_c.h, (WP), A[zz], false); \
} while (0)
#else
#define SAMP(A, zz, uu, WP, WF) do { \
    A[zz] += __uint_as_float(uu); \
    A[zz]  = fmaf((WF), __uint_as_float((uu) << 16), A[zz]); \
} while (0)
#endif

#define SAMPLE8(A, WP, WF) do { \
    SAMP(A, 0, q0.x, WP, WF); SAMP(A, 1, q0.y, WP, WF); \
    SAMP(A, 2, q0.z, WP, WF); SAMP(A, 3, q0.w, WP, WF); \
    SAMP(A, 4, q1.x, WP, WF); SAMP(A, 5, q1.y, WP, WF); \
    SAMP(A, 6, q1.z, WP, WF); SAMP(A, 7, q1.w, WP, WF); \
} while (0)

// 16x16 pixel tile, 128 threads (8x16), 2 adjacent x-pixels + ZG=8 z per thread.
// Identical structure to the 532us R1 kernel (fdot2 samples, divergent masked
// px1 reload, one barrier/view, double-buffered stage) -- the ONLY change is
// z-split 4: per-CU LDS bytes / staging traffic / fdot2 count are unchanged,
// but resident waves double (16/CU) to hide LDS + barrier latency.
__global__ __launch_bounds__(128, 4) void bp_lds(const uint* __restrict__ packed,
                                                 float* __restrict__ out) {
    __shared__ float4 tab[NVIEW];                        // 11520 B
    __shared__ __align__(16) uint stage[2][NR * RS];     // 2 x 1152 B

    const int tid = threadIdx.y * 8 + threadIdx.x;       // 0..127
    const int g   = blockIdx.z;                          // z-group 0..3 (8 z each)
    const float xf0 = (float)(int)(blockIdx.x * 16) - 255.5f;
    const float yf0 = (float)(int)(blockIdx.y * 16) - 255.5f;

    // Per-view cos/sin + block-uniform floor(t_min) folded as bval = 511.5 - imin.
    // bval fold perturbs t by <= 1 ULP(512); trunc at 0 and NR slack absorb it.
    for (int v = tid; v < NVIEW; v += 128) {
        float th = (float)v * (float)(M_PI / NVIEW);
        float s, c;
        sincosf(th, &s, &c);
        float b0 = fmaf(yf0, s, 511.5f);
        float b1 = fmaf(yf0 + 15.0f, s, 511.5f);
        float t00 = fmaf(xf0, c, b0);
        float t10 = fmaf(xf0 + 15.0f, c, b0);
        float t01 = fmaf(xf0, c, b1);
        float t11 = fmaf(xf0 + 15.0f, c, b1);
        int imin = (int)fminf(fminf(t00, t10), fminf(t01, t11));
        tab[v] = make_float4(c, s, 511.5f - (float)imin, __int_as_float(imin));
    }
    __syncthreads();

    const int x0 = blockIdx.x * 16 + threadIdx.x * 2;    // even
    const int y  = blockIdx.y * 16 + threadIdx.y;
    const float xf = (float)x0 - 255.5f;
    const float yf = (float)y  - 255.5f;

    float acc0[ZG], acc1[ZG];
    #pragma unroll
    for (int z = 0; z < ZG; ++z) { acc0[z] = 0.0f; acc1[z] = 0.0f; }

    // Staging: NR rows x 8 dw = 48 x4-chunks over 2 waves (24 lanes each).
    const int  wv   = tid >> 6;
    const int  ln   = tid & 63;
    const bool sact = (ln < 24);
    const int  slot = wv * 24 + ln;          // 0..47
    const int  sr   = slot >> 1;             // staged row 0..23
    const int  sch  = slot & 1;              // 16B chunk 0..1
    const size_t sg_off = ((size_t)sr << 5) + (g << 3) + (sch << 2);  // global dw off
    const int  swr  = sr * RS + (sch << 2);                           // LDS dw off

    // ---- prologue: stage view 0 into buffer 0 ----
    float4 t4 = tab[0];
    uint4 st;
    if (sact) {
        st = *(const uint4*)(packed + ((size_t)__float_as_int(t4.w) << 5) + sg_off);
        *(uint4*)&stage[0][swr] = st;
    }
    __syncthreads();

    #pragma unroll 2
    for (int v = 0; v < NVIEW; ++v) {
        // [A] next-view tab read + staging load (published at [F]; ~full view flight)
        float4 t4n = t4;
        if (v + 1 < NVIEW) t4n = tab[v + 1];
        if (sact && v + 1 < NVIEW) {
            st = *(const uint4*)(packed + ((size_t)(v + 1) << 15)
                                 + ((size_t)__float_as_int(t4n.w) << 5) + sg_off);
        }

        const float c = t4.x;
        float t0 = fmaf(xf, c, fmaf(yf, t4.y, t4.z));   // t - imin, >= -1ulp
        float t1 = t0 + c;
        int   i0 = (int)t0;                              // trunc(-eps) = 0: safe
        int   i1 = (int)t1;
        float w0 = t0 - (float)i0;
        float w1 = t1 - (float)i1;

#if USE_FDOT2
        half2v wp0; wp0[0] = (_Float16)1.0f; wp0[1] = (_Float16)w0;
        half2v wp1; wp1[0] = (_Float16)1.0f; wp1[1] = (_Float16)w1;
#else
        const int wp0 = 0, wp1 = 0;  // unused tokens in fallback
#endif

        // [C] px0 gather: 2x b128 off one base (imm offsets 0/16 B)
        const uint* sp = stage[v & 1] + i0 * RS;
        uint4 q0 = *(const uint4*)(sp);
        uint4 q1 = *(const uint4*)(sp + 4);

        SAMPLE8(acc0, wp0, w0);

        // [D] px1 gather only where the row differs (divergent mask; inactive
        // lanes keep px0's row in q, which is exactly px1's row for them)
        if (i1 != i0) {
            const uint* sp1 = stage[v & 1] + i1 * RS;
            q0 = *(const uint4*)(sp1);
            q1 = *(const uint4*)(sp1 + 4);
        }

        SAMPLE8(acc1, wp1, w1);

        // [F] publish view v+1 stage (vmcnt waits only on st, issued at [A])
        if (sact && v + 1 < NVIEW) *(uint4*)&stage[(v + 1) & 1][swr] = st;
        // [G] one barrier per view: orders iter-(v+1) writes of a buffer after
        // all iter-v reads of it -> race-free double buffer
        __syncthreads();
        t4 = t4n;
    }

    const float scale = 0.0043633231299858236f;  // pi / 720
    #pragma unroll
    for (int lz = 0; lz < ZG; ++lz) {
        float2 o = make_float2(acc0[lz] * scale, acc1[lz] * scale);
        *(float2*)(out + (((size_t)(g * ZG + lz)) * NY + y) * NX + x0) = o;
    }
}

// Fallback (ws too small for packed array): direct fp32, two loads per sample.
__global__ __launch_bounds__(256) void bp_direct(const float* __restrict__ xin,
                                                 float* __restrict__ out) {
    __shared__ float2 cs[NVIEW];
    int lt = threadIdx.y * 64 + threadIdx.x;
    for (int v = lt; v < NVIEW; v += 256) {
        float th = (float)v * (float)(M_PI / NVIEW);
        float s, c;
        sincosf(th, &s, &c);
        cs[v] = make_float2(c, s);
    }
    __syncthreads();

    int x = blockIdx.x * 64 + threadIdx.x;
    int y = blockIdx.y * 4 + threadIdx.y;
    float xf = (float)x - 255.5f;
    float yf = (float)y - 255.5f;

    float acc[NZ];
    #pragma unroll
    for (int z = 0; z < NZ; ++z) acc[z] = 0.0f;

    for (int v = 0; v < NVIEW; ++v) {
        float2 a = cs[v];
        float t  = fmaf(xf, a.x, fmaf(yf, a.y, 511.5f));
        int   i0 = (int)t;
        float w  = t - (float)i0;
        const float* p = xin + (size_t)v * NDCT + i0;
        #pragma unroll
        for (int z = 0; z < NZ; ++z) {
            float g0 = p[(size_t)z * NVIEW * NDCT];
            float g1 = p[(size_t)z * NVIEW * NDCT + 1];
            acc[z] += fmaf(w, g1 - g0, g0);
        }
    }

    const float scale = 0.0043633231299858236f;
    #pragma unroll
    for (int z = 0; z < NZ; ++z) {
        out[((size_t)z * NY + y) * NX + x] = acc[z] * scale;
    }
}

extern "C" void kernel_launch(void* const* d_in, const int* in_sizes, int n_in,
                              void* d_out, int out_size, void* d_ws, size_t ws_size,
                              hipStream_t stream) {
    const float* x = (const float*)d_in[0];
    float* out = (float*)d_out;

    const size_t packed_bytes = (size_t)NVIEW * NDCT * NZ * sizeof(uint);  // 94.4 MB

    if (ws_size >= packed_bytes) {
        uint* packed = (uint*)d_ws;
        pack_kernel<<<dim3(NVIEW, NDCT / 64), 64, 0, stream>>>(x, packed);
        bp_lds<<<dim3(NX / 16, NY / 16, NZ / ZG), dim3(8, 16), 0, stream>>>(packed, out);
    } else {
        bp_direct<<<dim3(NX / 64, NY / 4), dim3(64, 4), 0, stream>>>(x, out);
    }
}

// Round 6
// 717.666 us; speedup vs baseline: 1.2212x; 1.2013x over previous
//
#include <hip/hip_runtime.h>
#include <math.h>

#define NVIEW 720
#define NDCT  1024
#define NZ    32
#define NX    512
#define NY    512

#define TS   32      // pixel tile 32x32 (halves staged-row lines per pixel vs 16x16)
#define ZG   16      // z per block; 2 z-groups, packed layout SPLIT by group so
                     // every staged line is fully consumed by its block
#define NR   48      // staged rows: 31*(|c|+|s|)+1 <= 44.9, +1 for i+1, +pad -> 48
#define RS   20      // dwords per staged row (16 data + 4 pad; 80 B). b128 start of
                     // row r = 20r mod 32 = {0,20,8,28,16,4,24,12} over r mod 8:
                     // injective -> only dr in {8,16,24} alias (measured-free class).
#define GSTRIDE ((size_t)NVIEW * NDCT * 16)   // dw per z-group region (47.2 MB)

typedef unsigned int uint;

#if __has_builtin(__builtin_amdgcn_fdot2)
#define USE_FDOT2 1
typedef _Float16 half2v __attribute__((ext_vector_type(2)));
#else
#define USE_FDOT2 0
#endif

// Round fp32 -> bf16 bits (RNE).
__device__ __forceinline__ uint f2bf_rne(float f) {
    uint u = __float_as_uint(f);
    return (u + 0x7fffu + ((u >> 16) & 1u)) >> 16;
}

// Packed word for (v, i, z):
//  fdot2 path:  lo16 = f16(g0 = p[i]), hi16 = f16(d = p[i+1]-p[i])
//               consumer: acc = v_dot2_f32_f16(word, {1.0, w}, acc)
//  fallback:    hi16 = dithered bf16(g0), lo16 = bf16(d)
__device__ __forceinline__ uint pack_word(float a, float b) {
#if USE_FDOT2
    union { _Float16 h[2]; uint u; } r;
    r.h[0] = (_Float16)a;         // g0 in low half
    r.h[1] = (_Float16)(b - a);   // d  in high half
    return r.u;
#else
    uint lo = f2bf_rne(b - a);
    uint u  = (f2bf_rne(a) << 16) | lo;
    uint up = u + 0x10000u, um = u - 0x10000u;
    float e0 = fabsf(__uint_as_float(u)  - a);
    float e1 = fabsf(__uint_as_float(up) - a);
    float e2 = fabsf(__uint_as_float(um) - a);
    if (e1 < e0) { u = up; e0 = e1; }
    if (e2 < e0) { u = um; }
    return u;
#endif
}

// packed[g][v][i][z16], g = z>>4: z-group-split so each bp block reads only
// full 128B lines (2 rows/line) from its own region. Same transpose as before;
// only the store addressing changes.
__global__ __launch_bounds__(64) void pack_kernel(const float* __restrict__ x,
                                                  uint* __restrict__ packed) {
    __shared__ uint tr[64 * 33];             // [i_local][z], stride 33 -> conflict-free
    const int l  = threadIdx.x;              // 0..63
    const int v  = blockIdx.x;               // 0..719
    const int ib = blockIdx.y * 64;          // i block base
    const bool last = (ib + 64 >= NDCT);
    const float* rowbase = x + (size_t)v * NDCT + ib;

    float pre = 0.0f;
    if (l < NZ && !last) pre = rowbase[(size_t)l * (NVIEW * NDCT) + 64];

    for (int z = 0; z < NZ; ++z) {
        const float* r = rowbase + (size_t)z * (NVIEW * NDCT);
        float a   = r[l];                    // coalesced 256B
        float a64 = __shfl(pre, z);
        float b   = __shfl(a, l + 1);
        if (l == 63) b = a64;                // neighbor across wave boundary
        tr[l * 33 + z] = pack_word(a, b);
    }
    __syncthreads();

    #pragma unroll
    for (int it = 0; it < 8; ++it) {
        int c  = it * 64 + l;                // chunk 0..511
        int il = c >> 3;
        int zc = (c & 7) * 4;
        int gg = zc >> 4;                    // z-group region
        int zl = zc & 15;
        uint4 w4;
        w4.x = tr[il * 33 + zc + 0];
        w4.y = tr[il * 33 + zc + 1];
        w4.z = tr[il * 33 + zc + 2];
        w4.w = tr[il * 33 + zc + 3];
        uint* dst = packed + (size_t)gg * GSTRIDE
                  + ((size_t)(v * NDCT + ib + il) << 4) + zl;
        *(uint4*)dst = w4;                   // 16B chunks, region-contiguous
    }
}

#if USE_FDOT2
#define SAMP(A, zz, uu, WP, WF) do { \
    union { uint q; half2v h; } _c; _c.q = (uu); \
    A[zz] = __builtin_amdgcn_fdot2(_c.h, (WP), A[zz], false); \
} while (0)
#else
#define SAMP(A, zz, uu, WP, WF) do { \
    A[zz] += __uint_as_float(uu); \
    A[zz]  = fmaf((WF), __uint_as_float((uu) << 16), A[zz]); \
} while (0)
#endif

#define SAMPLE16(A, WP, WF) do { \
    SAMP(A, 0, q0.x, WP, WF); SAMP(A, 1, q0.y, WP, WF); \
    SAMP(A, 2, q0.z, WP, WF); SAMP(A, 3, q0.w, WP, WF); \
    SAMP(A, 4, q1.x, WP, WF); SAMP(A, 5, q1.y, WP, WF); \
    SAMP(A, 6, q1.z, WP, WF); SAMP(A, 7, q1.w, WP, WF); \
    SAMP(A, 8, q2.x, WP, WF); SAMP(A, 9, q2.y, WP, WF); \
    SAMP(A,10, q2.z, WP, WF); SAMP(A,11, q2.w, WP, WF); \
    SAMP(A,12, q3.x, WP, WF); SAMP(A,13, q3.y, WP, WF); \
    SAMP(A,14, q3.z, WP, WF); SAMP(A,15, q3.w, WP, WF); \
} while (0)

// 32x32 pixel tile, 512 threads (16x32), 2 adjacent x-pixels + 16 z per thread.
// Inner loop is the proven 532us R1 pattern verbatim (fdot2 samples, divergent
// masked px1 reload, one barrier/view, double-buffered stage, 16 waves/CU).
// Changes vs R1 attack ONLY the HBM staging fetch (R5 isolated it as the
// limiter): z-split packed regions (full-line reads) + 4x fewer tiles with 2x
// rows each -> line-touches/view drop 49152 -> 12288 (-75%).
__global__ __launch_bounds__(512, 4) void bp_lds(const uint* __restrict__ packed,
                                                 float* __restrict__ out) {
    __shared__ float4 tab[NVIEW];                        // 11520 B
    __shared__ __align__(16) uint stage[2][NR * RS];     // 2 x 3840 B

    const int tid = threadIdx.y * 16 + threadIdx.x;      // 0..511
    const int g   = blockIdx.z;                          // z-group 0..1
    const float xf0 = (float)(int)(blockIdx.x * TS) - 255.5f;
    const float yf0 = (float)(int)(blockIdx.y * TS) - 255.5f;

    // Per-view cos/sin + block-uniform floor(t_min) folded as bval = 511.5 - imin.
    // bval fold perturbs t by <= 1 ULP(512); trunc at 0 and NR slack absorb it.
    for (int v = tid; v < NVIEW; v += 512) {
        float th = (float)v * (float)(M_PI / NVIEW);
        float s, c;
        sincosf(th, &s, &c);
        float b0 = fmaf(yf0, s, 511.5f);
        float b1 = fmaf(yf0 + (float)(TS - 1), s, 511.5f);
        float t00 = fmaf(xf0, c, b0);
        float t10 = fmaf(xf0 + (float)(TS - 1), c, b0);
        float t01 = fmaf(xf0, c, b1);
        float t11 = fmaf(xf0 + (float)(TS - 1), c, b1);
        int imin = (int)fminf(fminf(t00, t10), fminf(t01, t11));
        tab[v] = make_float4(c, s, 511.5f - (float)imin, __int_as_float(imin));
    }
    __syncthreads();

    const int x0 = blockIdx.x * TS + threadIdx.x * 2;    // even
    const int y  = blockIdx.y * TS + threadIdx.y;
    const float xf = (float)x0 - 255.5f;
    const float yf = (float)y  - 255.5f;

    float acc0[ZG], acc1[ZG];
    #pragma unroll
    for (int z = 0; z < ZG; ++z) { acc0[z] = 0.0f; acc1[z] = 0.0f; }

    // Staging: NR rows x 16 dw = 192 x4-chunks over 8 waves (24 lanes each).
    // Global span is CONTIGUOUS 3072 B (region layout): 24 full 128B lines.
    const int  wv   = tid >> 6;
    const int  ln   = tid & 63;
    const bool sact = (ln < 24);
    const int  slot = wv * 24 + ln;          // 0..191
    const int  sr   = slot >> 2;             // staged row 0..47
    const int  sch  = slot & 3;              // 16B chunk 0..3
    const size_t sg_off = ((size_t)sr << 4) + (sch << 2);   // dw off within window
    const int  swr  = sr * RS + (sch << 2);                 // LDS dw off
    const uint* greg = packed + (size_t)g * GSTRIDE;        // this block's region

    // ---- prologue: stage view 0 into buffer 0 ----
    float4 t4 = tab[0];
    uint4 st;
    if (sact) {
        st = *(const uint4*)(greg + ((size_t)__float_as_int(t4.w) << 4) + sg_off);
        *(uint4*)&stage[0][swr] = st;
    }
    __syncthreads();

    #pragma unroll 2
    for (int v = 0; v < NVIEW; ++v) {
        // [A] next-view tab read + staging load (published at [F]; ~full view flight)
        float4 t4n = t4;
        if (v + 1 < NVIEW) t4n = tab[v + 1];
        if (sact && v + 1 < NVIEW) {
            st = *(const uint4*)(greg + ((size_t)(v + 1) << 14)
                                 + ((size_t)__float_as_int(t4n.w) << 4) + sg_off);
        }

        const float c = t4.x;
        float t0 = fmaf(xf, c, fmaf(yf, t4.y, t4.z));   // t - imin, >= -1ulp
        float t1 = t0 + c;
        int   i0 = (int)t0;                              // trunc(-eps) = 0: safe
        int   i1 = (int)t1;
        float w0 = t0 - (float)i0;
        float w1 = t1 - (float)i1;

#if USE_FDOT2
        half2v wp0; wp0[0] = (_Float16)1.0f; wp0[1] = (_Float16)w0;
        half2v wp1; wp1[0] = (_Float16)1.0f; wp1[1] = (_Float16)w1;
#else
        const int wp0 = 0, wp1 = 0;  // unused tokens in fallback
#endif

        // [C] px0 gather: 4x b128 off one base (imm offsets 0/16/32/48 B)
        const uint* sp = stage[v & 1] + i0 * RS;
        uint4 q0 = *(const uint4*)(sp);
        uint4 q1 = *(const uint4*)(sp + 4);
        uint4 q2 = *(const uint4*)(sp + 8);
        uint4 q3 = *(const uint4*)(sp + 12);

        SAMPLE16(acc0, wp0, w0);

        // [D] px1 gather only where the row differs (divergent mask; inactive
        // lanes keep px0's row in q, which is exactly px1's row for them)
        if (i1 != i0) {
            const uint* sp1 = stage[v & 1] + i1 * RS;
            q0 = *(const uint4*)(sp1);
            q1 = *(const uint4*)(sp1 + 4);
            q2 = *(const uint4*)(sp1 + 8);
            q3 = *(const uint4*)(sp1 + 12);
        }

        SAMPLE16(acc1, wp1, w1);

        // [F] publish view v+1 stage (vmcnt waits only on st, issued at [A])
        if (sact && v + 1 < NVIEW) *(uint4*)&stage[(v + 1) & 1][swr] = st;
        // [G] one barrier per view: orders iter-(v+1) writes of a buffer after
        // all iter-v reads of it -> race-free double buffer
        __syncthreads();
        t4 = t4n;
    }

    const float scale = 0.0043633231299858236f;  // pi / 720
    #pragma unroll
    for (int lz = 0; lz < ZG; ++lz) {
        float2 o = make_float2(acc0[lz] * scale, acc1[lz] * scale);
        *(float2*)(out + (((size_t)(g * ZG + lz)) * NY + y) * NX + x0) = o;
    }
}

// Fallback (ws too small for packed array): direct fp32, two loads per sample.
__global__ __launch_bounds__(256) void bp_direct(const float* __restrict__ xin,
                                                 float* __restrict__ out) {
    __shared__ float2 cs[NVIEW];
    int lt = threadIdx.y * 64 + threadIdx.x;
    for (int v = lt; v < NVIEW; v += 256) {
        float th = (float)v * (float)(M_PI / NVIEW);
        float s, c;
        sincosf(th, &s, &c);
        cs[v] = make_float2(c, s);
    }
    __syncthreads();

    int x = blockIdx.x * 64 + threadIdx.x;
    int y = blockIdx.y * 4 + threadIdx.y;
    float xf = (float)x - 255.5f;
    float yf = (float)y - 255.5f;

    float acc[NZ];
    #pragma unroll
    for (int z = 0; z < NZ; ++z) acc[z] = 0.0f;

    for (int v = 0; v < NVIEW; ++v) {
        float2 a = cs[v];
        float t  = fmaf(xf, a.x, fmaf(yf, a.y, 511.5f));
        int   i0 = (int)t;
        float w  = t - (float)i0;
        const float* p = xin + (size_t)v * NDCT + i0;
        #pragma unroll
        for (int z = 0; z < NZ; ++z) {
            float g0 = p[(size_t)z * NVIEW * NDCT];
            float g1 = p[(size_t)z * NVIEW * NDCT + 1];
            acc[z] += fmaf(w, g1 - g0, g0);
        }
    }

    const float scale = 0.0043633231299858236f;
    #pragma unroll
    for (int z = 0; z < NZ; ++z) {
        out[((size_t)z * NY + y) * NX + x] = acc[z] * scale;
    }
}

extern "C" void kernel_launch(void* const* d_in, const int* in_sizes, int n_in,
                              void* d_out, int out_size, void* d_ws, size_t ws_size,
                              hipStream_t stream) {
    const float* x = (const float*)d_in[0];
    float* out = (float*)d_out;

    const size_t packed_bytes = 2 * GSTRIDE * sizeof(uint);   // 94.4 MB

    if (ws_size >= packed_bytes) {
        uint* packed = (uint*)d_ws;
        pack_kernel<<<dim3(NVIEW, NDCT / 64), 64, 0, stream>>>(x, packed);
        bp_lds<<<dim3(NX / TS, NY / TS, 2), dim3(16, 32), 0, stream>>>(packed, out);
    } else {
        bp_direct<<<dim3(NX / 64, NY / 4), dim3(64, 4), 0, stream>>>(x, out);
    }
}